// Round 8
// baseline (213.756 us; speedup 1.0000x reference)
//
#include <hip/hip_runtime.h>

// Problem constants (fixed by setup_inputs)
#define HW   256
#define Bb   4
#define Nn   256       // K keypoints (per image batch)
#define Pp   33
#define PPAD 36        // padded patch row (float)
#define OUTF 128
#define SIG  16

// conv1-output plane (bf16 hi only) for MFMA A-operands:
// [rowslot 6][parity 2][col' 16][kc 40 (32 used + 8 pad)] ushort.
#define KCP   40
#define PLROW (2 * 16 * KCP)       // shorts per row-slot = 1280
#define PLSZ  (6 * PLROW)          // 7680 shorts

// ws layout (float offsets)
#define WS_W1R  0        // [32][28] f32 = 896 (per-channel k-major, pad 27->28)
#define WS_BHI  896      // 18432 ushort = 9216 f  (B-frags hi, frag-ordered)
#define WS_BLO  10112    // 18432 ushort = 9216 f  (B-frags lo)
#define WS_WLT  19328    // [64][128] f32 = 8192

typedef __attribute__((ext_vector_type(8))) short v8s;    // 8 bf16 (4 VGPRs)
typedef __attribute__((ext_vector_type(4))) float f32x4;  // MFMA acc

__device__ __forceinline__ unsigned short f2bf_rne(float x) {
  unsigned u = __float_as_uint(x);
  unsigned r = (u + 0x7FFFu + ((u >> 16) & 1u)) >> 16;
  return (unsigned short)r;
}
__device__ __forceinline__ float bf2f(unsigned short h) {
  return __uint_as_float(((unsigned)h) << 16);
}

__global__ __launch_bounds__(256) void prep_kernel(
    const float* __restrict__ w1, const float* __restrict__ w2,
    const float* __restrict__ wl, float* __restrict__ ws,
    float* __restrict__ out) {
  int t = blockIdx.x * 256 + threadIdx.x;
  int stride = gridDim.x * 256;
  if (blockIdx.x == 0 && threadIdx.x == 0) out[0] = 0.0f;   // replaces memset
  for (int i = t; i < 896; i += stride) {        // w1r[ch][28]
    int ch = i / 28, k = i - ch * 28;
    ws[WS_W1R + i] = (k < 27) ? w1[ch * 27 + k] : 0.0f;
  }
  // B-fragments for mfma_f32_16x16x32_bf16:
  // element j of lane l, wave w, tap t: n(ch) = w*16 + (l&15), k(kc) = (l>>4)*8 + j
  unsigned short* bhi = (unsigned short*)(ws + WS_BHI);
  unsigned short* blo = (unsigned short*)(ws + WS_BLO);
  for (int i = t; i < 18432; i += stride) {
    int j  = i & 7;
    int l  = (i >> 3) & 63;
    int w  = (i >> 9) & 3;
    int tp = i >> 11;              // 0..8 = ky*3+kx
    int ch = w * 16 + (l & 15);
    int kc = ((l >> 4) << 3) + j;
    int ky = tp / 3, kx = tp - ky * 3;
    float v = w2[ch * 288 + kc * 9 + ky * 3 + kx];
    unsigned short h = f2bf_rne(v);
    bhi[i] = h;
    blo[i] = f2bf_rne(v - bf2f(h));
  }
  for (int i = t; i < 8192; i += stride) {       // wlt[i64][o128]
    int o = i & 127, ii = i >> 7;
    ws[WS_WLT + i] = wl[o * 64 + ii];
  }
}

// One block per (n,b) keypoint-sample; both sides computed in-block; MSE via
// one float atomicAdd per block. 256 threads = 4 waves.
// B-fragments are loaded from global ws INSIDE the tap loop (L2-resident after
// first touch) instead of register arrays: R7 held 72 VGPRs of frags, which
// blew the launch_bounds(256,4) 128-VGPR cap and spilled ~64 MB to scratch
// (FETCH 61 MB / WRITE 67 MB at VGPR=64).
__global__ __launch_bounds__(256, 4) void patch_cnn_kernel(
    const float* __restrict__ imgG, const float* __restrict__ imgS,
    const float* __restrict__ kpG,  const float* __restrict__ kpS,
    const float* __restrict__ b1g,  const float* __restrict__ b2g,
    const float* __restrict__ blg,  const float* __restrict__ ws,
    float* __restrict__ out) {
  __shared__ __align__(16) float patch[3 * Pp * PPAD];     // 14256 B
  __shared__ __align__(16) unsigned short hiP[PLSZ];       // 15360 B
  __shared__ __align__(16) float w1l[32 * 28];             // 3584 B
  __shared__ float b1l[32];
  __shared__ float gapv[64];
  __shared__ float fstash[OUTF];
  __shared__ float lred[4];
  // total ~= 34.3 KB -> 4 blocks/CU

  const int bid  = blockIdx.x;          // grid 1024
  const int n    = bid >> 2;
  const int b    = bid & 3;
  const int tid  = threadIdx.x;
  const int wave = tid >> 6;
  const int lane = tid & 63;

  // conv1 roles
  const int rw  = wave & 1;
  const int q8  = wave >> 1;
  const int kcL = lane & 31;
  const int chf = lane >> 5;
  const int c0  = q8 * 16 + chf * 8;
  // conv2 roles
  const int m = lane & 15;
  const int q = lane >> 4;

  // per-thread B-frag base pointers (global, L2-resident); frag t at [t*256]
  const v8s* bhW = (const v8s*)((const unsigned short*)(ws + WS_BHI)) +
                   (wave * 64 + lane);
  const v8s* blW = (const v8s*)((const unsigned short*)(ws + WS_BLO)) +
                   (wave * 64 + lane);
  const float b2v = b2g[wave * 16 + m];

  // conv1 producer: rows r0,r0+1 -> plane slots ps,ps+1 (hi plane only)
  auto produce = [&](int r0, int ps) {
    const int row = r0 + rw;
    if (row <= 30) {
      int sl = ps + rw; if (sl >= 6) sl -= 6;
      const float bb = b1l[kcL];
      float4 wv[7];
      const float4* wsrc = (const float4*)&w1l[kcL * 28];
#pragma unroll
      for (int u = 0; u < 7; ++u) wv[u] = wsrc[u];
      const float* wr = (const float*)wv;
      float o[8];
#pragma unroll
      for (int u = 0; u < 8; ++u) o[u] = bb;
#pragma unroll
      for (int ci = 0; ci < 3; ++ci) {
#pragma unroll
        for (int ky = 0; ky < 3; ++ky) {
          const float* pr = &patch[(ci * Pp + row + ky) * PPAD + c0];
          float4 A = *(const float4*)pr;
          float4 Bv = *(const float4*)(pr + 4);
          float2 Cv = *(const float2*)(pr + 8);
          float vv[10] = {A.x, A.y, A.z, A.w, Bv.x, Bv.y, Bv.z, Bv.w, Cv.x, Cv.y};
          const int k = (ci * 3 + ky) * 3;
#pragma unroll
          for (int kx = 0; kx < 3; ++kx)
#pragma unroll
            for (int u = 0; u < 8; ++u) o[u] = fmaf(vv[u + kx], wr[k + kx], o[u]);
        }
      }
#pragma unroll
      for (int u = 0; u < 8; ++u) {
        float f = fmaxf(o[u], 0.0f);
        const int c = c0 + u;
        const int idx = ((sl * 2 + (c & 1)) * 16 + (c >> 1)) * KCP + kcL;
        hiP[idx] = f2bf_rne(f);
      }
    }
  };

  float dd = 0.0f;   // per-thread squared-diff contribution

#pragma unroll 1
  for (int side = 0; side < 2; ++side) {
    const float* img = side ? imgS : imgG;
    const float* kp  = side ? kpS : kpG;

    int sx = (int)floorf(kp[n * 2 + 0] * 256.0f) - SIG;
    int sy = (int)floorf(kp[n * 2 + 1] * 256.0f) - SIG;
    sx = min(max(sx, 0), HW - Pp);
    sy = min(max(sy, 0), HW - Pp);

    // stage patch (zero pad cols)
    for (int i = tid; i < 3 * Pp * PPAD; i += 256) {
      int ci = i / (Pp * PPAD);
      int r2 = i - ci * (Pp * PPAD);
      int r  = r2 / PPAD;
      int cc = r2 - r * PPAD;
      float v = 0.0f;
      if (cc < Pp) v = img[((b * 3 + ci) * HW + (sy + r)) * HW + (sx + cc)];
      patch[i] = v;
    }
    if (side == 0) {
      for (int i = tid; i < 896; i += 256) w1l[i] = ws[WS_W1R + i];
      if (tid < 32) b1l[tid] = b1g[tid];
    }
    __syncthreads();           // patch (and w1l) ready

    float gapAcc = 0.0f;
    produce(0, 0);
    produce(2, 2);

    int s0 = 0;
#pragma unroll 1
    for (int y2 = 0; y2 < 15; ++y2) {
      __syncthreads();         // producer writes visible
      f32x4 acc = {0.f, 0.f, 0.f, 0.f};
#pragma unroll
      for (int ky = 0; ky < 3; ++ky) {
        int sk = s0 + ky; if (sk >= 6) sk -= 6;
#pragma unroll
        for (int kx = 0; kx < 3; ++kx) {
          const int p = kx & 1;
          int cp = m + (kx >> 1); if (cp > 15) cp = 15;
          const int idx = ((sk * 2 + p) * 16 + cp) * KCP + q * 8;
          v8s ah = *(const v8s*)&hiP[idx];
          const int t = ky * 3 + kx;
          v8s bh = bhW[t * 256];       // global, L2-hit
          v8s bl = blW[t * 256];
          acc = __builtin_amdgcn_mfma_f32_16x16x32_bf16(ah, bh, acc, 0, 0, 0);
          acc = __builtin_amdgcn_mfma_f32_16x16x32_bf16(ah, bl, acc, 0, 0, 0);
        }
      }
      {
        float s = fmaxf(acc.x + b2v, 0.f) + fmaxf(acc.y + b2v, 0.f) +
                  fmaxf(acc.z + b2v, 0.f);
        if (q < 3) s += fmaxf(acc.w + b2v, 0.f);   // x=15 row is pad
        gapAcc += s;
      }
      const int r0 = 2 * y2 + 4;
      if (r0 <= 30) {
        int ps = s0 + 4; if (ps >= 6) ps -= 6;
        produce(r0, ps);
      }
      s0 += 2; if (s0 >= 6) s0 -= 6;
    }

    // reduce gapAcc over kc-quads (lanes m, m+16, m+32, m+48)
    gapAcc += __shfl_down(gapAcc, 32, 64);
    gapAcc += __shfl_down(gapAcc, 16, 64);
    if (lane < 16) gapv[wave * 16 + m] = gapAcc * (1.0f / 225.0f);
    __syncthreads();

    if (tid < OUTF) {
      float f = blg[tid];
#pragma unroll 8
      for (int i = 0; i < 64; ++i) f = fmaf(gapv[i], ws[WS_WLT + i * OUTF + tid], f);
      if (side == 0) {
        fstash[tid] = f;
      } else {
        float d = f - fstash[tid];
        dd = d * d;
      }
    }
    __syncthreads();           // fstash/gapv settled before next side reuses LDS
  }

  // block reduction of dd -> one atomicAdd
  dd += __shfl_down(dd, 32, 64);
  dd += __shfl_down(dd, 16, 64);
  dd += __shfl_down(dd, 8, 64);
  dd += __shfl_down(dd, 4, 64);
  dd += __shfl_down(dd, 2, 64);
  dd += __shfl_down(dd, 1, 64);
  if (lane == 0) lred[wave] = dd;
  __syncthreads();
  if (tid == 0) {
    float s = (lred[0] + lred[1]) + (lred[2] + lred[3]);
    atomicAdd(out, s * (1.0f / 131072.0f));
  }
}

extern "C" void kernel_launch(void* const* d_in, const int* in_sizes, int n_in,
                              void* d_out, int out_size, void* d_ws, size_t ws_size,
                              hipStream_t stream) {
  const float* imgG = (const float*)d_in[0];
  const float* imgS = (const float*)d_in[1];
  const float* kpG  = (const float*)d_in[2];
  const float* kpS  = (const float*)d_in[3];
  const float* w1   = (const float*)d_in[4];
  const float* b1   = (const float*)d_in[5];
  const float* w2   = (const float*)d_in[6];
  const float* b2   = (const float*)d_in[7];
  const float* wl   = (const float*)d_in[8];
  const float* bl   = (const float*)d_in[9];
  float* ws  = (float*)d_ws;
  float* out = (float*)d_out;

  hipLaunchKernelGGL(prep_kernel, dim3(32), dim3(256), 0, stream, w1, w2, wl, ws, out);
  hipLaunchKernelGGL(patch_cnn_kernel, dim3(1024), dim3(256), 0, stream,
                     imgG, imgS, kpG, kpS, b1, b2, bl, ws, out);
}

// Round 9
// 188.494 us; speedup vs baseline: 1.1340x; 1.1340x over previous
//
#include <hip/hip_runtime.h>

// Problem constants (fixed by setup_inputs)
#define HW   256
#define Bb   4
#define Nn   256       // K keypoints (per image batch)
#define Pp   33
#define PPAD 36        // padded patch row (float)
#define OUTF 128
#define SIG  16

// conv1-output plane (bf16 hi only) for MFMA A-operands:
// [rowslot 6][parity 2][col' 16][kc 40 (32 used + 8 pad)] ushort.
#define KCP   40
#define PLROW (2 * 16 * KCP)       // shorts per row-slot = 1280
#define PLSZ  (6 * PLROW)          // 7680 shorts

// ws layout (float offsets)
#define WS_W1R  0        // [32][28] f32 = 896 (per-channel k-major, pad 27->28)
#define WS_BHI  896      // 18432 ushort = 9216 f  (B-frags hi, frag-ordered)
#define WS_BLO  10112    // 18432 ushort = 9216 f  (B-frags lo)
#define WS_WLT  19328    // [64][128] f32 = 8192

typedef __attribute__((ext_vector_type(8))) short v8s;    // 8 bf16 (4 VGPRs)
typedef __attribute__((ext_vector_type(4))) float f32x4;  // MFMA acc

__device__ __forceinline__ unsigned short f2bf_rne(float x) {
  unsigned u = __float_as_uint(x);
  unsigned r = (u + 0x7FFFu + ((u >> 16) & 1u)) >> 16;
  return (unsigned short)r;
}
__device__ __forceinline__ float bf2f(unsigned short h) {
  return __uint_as_float(((unsigned)h) << 16);
}

__global__ __launch_bounds__(256) void prep_kernel(
    const float* __restrict__ w1, const float* __restrict__ w2,
    const float* __restrict__ wl, float* __restrict__ ws,
    float* __restrict__ out) {
  int t = blockIdx.x * 256 + threadIdx.x;
  int stride = gridDim.x * 256;
  if (blockIdx.x == 0 && threadIdx.x == 0) out[0] = 0.0f;   // replaces memset
  for (int i = t; i < 896; i += stride) {        // w1r[ch][28]
    int ch = i / 28, k = i - ch * 28;
    ws[WS_W1R + i] = (k < 27) ? w1[ch * 27 + k] : 0.0f;
  }
  // B-fragments for mfma_f32_16x16x32_bf16:
  // element j of lane l, wave w, tap t: n(ch) = w*16 + (l&15), k(kc) = (l>>4)*8 + j
  unsigned short* bhi = (unsigned short*)(ws + WS_BHI);
  unsigned short* blo = (unsigned short*)(ws + WS_BLO);
  for (int i = t; i < 18432; i += stride) {
    int j  = i & 7;
    int l  = (i >> 3) & 63;
    int w  = (i >> 9) & 3;
    int tp = i >> 11;              // 0..8 = ky*3+kx
    int ch = w * 16 + (l & 15);
    int kc = ((l >> 4) << 3) + j;
    int ky = tp / 3, kx = tp - ky * 3;
    float v = w2[ch * 288 + kc * 9 + ky * 3 + kx];
    unsigned short h = f2bf_rne(v);
    bhi[i] = h;
    blo[i] = f2bf_rne(v - bf2f(h));
  }
  for (int i = t; i < 8192; i += stride) {       // wlt[i64][o128]
    int o = i & 127, ii = i >> 7;
    ws[WS_WLT + i] = wl[o * 64 + ii];
  }
}

// One block per (n,b) keypoint-sample; both sides computed in-block; MSE via
// one float atomicAdd per block. 256 threads = 4 waves.
// NOTE on launch bounds: plain __launch_bounds__(256), NO min-waves arg.
// R7/R8 used (256,4) and the backend's heuristic targeted a 64-VGPR budget
// (8 waves/EU) that LDS occupancy (34 KB -> 4 blocks/CU) can never use,
// spilling ~64 MB/dispatch to scratch (WRITE_SIZE 1 MB -> 64.5 MB, VGPR=64).
// R6 with no tight bound compiled to VGPR=84, zero spill.
__global__ __launch_bounds__(256) void patch_cnn_kernel(
    const float* __restrict__ imgG, const float* __restrict__ imgS,
    const float* __restrict__ kpG,  const float* __restrict__ kpS,
    const float* __restrict__ b1g,  const float* __restrict__ b2g,
    const float* __restrict__ blg,  const float* __restrict__ ws,
    float* __restrict__ out) {
  __shared__ __align__(16) float patch[3 * Pp * PPAD];     // 14256 B
  __shared__ __align__(16) unsigned short hiP[PLSZ];       // 15360 B
  __shared__ __align__(16) float w1l[32 * 28];             // 3584 B
  __shared__ float b1l[32];
  __shared__ float gapv[64];
  __shared__ float fstash[OUTF];
  __shared__ float lred[4];
  // total ~= 34.3 KB -> 4 blocks/CU by LDS

  const int bid  = blockIdx.x;          // grid 1024
  const int n    = bid >> 2;
  const int b    = bid & 3;
  const int tid  = threadIdx.x;
  const int wave = tid >> 6;
  const int lane = tid & 63;

  // conv1 roles
  const int rw  = wave & 1;
  const int q8  = wave >> 1;
  const int kcL = lane & 31;
  const int chf = lane >> 5;
  const int c0  = q8 * 16 + chf * 8;
  // conv2 roles
  const int m = lane & 15;
  const int q = lane >> 4;

  // per-thread B-frag base pointers (global, L2-resident); frag t at [t*256]
  const v8s* bhW = (const v8s*)((const unsigned short*)(ws + WS_BHI)) +
                   (wave * 64 + lane);
  const v8s* blW = (const v8s*)((const unsigned short*)(ws + WS_BLO)) +
                   (wave * 64 + lane);
  const float b2v = b2g[wave * 16 + m];

  // conv1 producer: rows r0,r0+1 -> plane slots ps,ps+1 (hi plane only)
  auto produce = [&](int r0, int ps) {
    const int row = r0 + rw;
    if (row <= 30) {
      int sl = ps + rw; if (sl >= 6) sl -= 6;
      const float bb = b1l[kcL];
      float4 wv[7];
      const float4* wsrc = (const float4*)&w1l[kcL * 28];
#pragma unroll
      for (int u = 0; u < 7; ++u) wv[u] = wsrc[u];
      const float* wr = (const float*)wv;
      float o[8];
#pragma unroll
      for (int u = 0; u < 8; ++u) o[u] = bb;
#pragma unroll
      for (int ci = 0; ci < 3; ++ci) {
#pragma unroll
        for (int ky = 0; ky < 3; ++ky) {
          const float* pr = &patch[(ci * Pp + row + ky) * PPAD + c0];
          float4 A = *(const float4*)pr;
          float4 Bv = *(const float4*)(pr + 4);
          float2 Cv = *(const float2*)(pr + 8);
          float vv[10] = {A.x, A.y, A.z, A.w, Bv.x, Bv.y, Bv.z, Bv.w, Cv.x, Cv.y};
          const int k = (ci * 3 + ky) * 3;
#pragma unroll
          for (int kx = 0; kx < 3; ++kx)
#pragma unroll
            for (int u = 0; u < 8; ++u) o[u] = fmaf(vv[u + kx], wr[k + kx], o[u]);
        }
      }
#pragma unroll
      for (int u = 0; u < 8; ++u) {
        float f = fmaxf(o[u], 0.0f);
        const int c = c0 + u;
        const int idx = ((sl * 2 + (c & 1)) * 16 + (c >> 1)) * KCP + kcL;
        hiP[idx] = f2bf_rne(f);
      }
    }
  };

  float dd = 0.0f;   // per-thread squared-diff contribution

#pragma unroll 1
  for (int side = 0; side < 2; ++side) {
    const float* img = side ? imgS : imgG;
    const float* kp  = side ? kpS : kpG;

    int sx = (int)floorf(kp[n * 2 + 0] * 256.0f) - SIG;
    int sy = (int)floorf(kp[n * 2 + 1] * 256.0f) - SIG;
    sx = min(max(sx, 0), HW - Pp);
    sy = min(max(sy, 0), HW - Pp);

    // stage patch (zero pad cols)
    for (int i = tid; i < 3 * Pp * PPAD; i += 256) {
      int ci = i / (Pp * PPAD);
      int r2 = i - ci * (Pp * PPAD);
      int r  = r2 / PPAD;
      int cc = r2 - r * PPAD;
      float v = 0.0f;
      if (cc < Pp) v = img[((b * 3 + ci) * HW + (sy + r)) * HW + (sx + cc)];
      patch[i] = v;
    }
    if (side == 0) {
      for (int i = tid; i < 896; i += 256) w1l[i] = ws[WS_W1R + i];
      if (tid < 32) b1l[tid] = b1g[tid];
    }
    __syncthreads();           // patch (and w1l) ready

    float gapAcc = 0.0f;
    produce(0, 0);
    produce(2, 2);

    int s0 = 0;
#pragma unroll 1
    for (int y2 = 0; y2 < 15; ++y2) {
      __syncthreads();         // producer writes visible
      f32x4 acc = {0.f, 0.f, 0.f, 0.f};
#pragma unroll
      for (int ky = 0; ky < 3; ++ky) {
        int sk = s0 + ky; if (sk >= 6) sk -= 6;
#pragma unroll
        for (int kx = 0; kx < 3; ++kx) {
          const int p = kx & 1;
          int cp = m + (kx >> 1); if (cp > 15) cp = 15;
          const int idx = ((sk * 2 + p) * 16 + cp) * KCP + q * 8;
          v8s ah = *(const v8s*)&hiP[idx];
          const int t = ky * 3 + kx;
          v8s bh = bhW[t * 256];       // global, L2-hit
          v8s bl = blW[t * 256];
          acc = __builtin_amdgcn_mfma_f32_16x16x32_bf16(ah, bh, acc, 0, 0, 0);
          acc = __builtin_amdgcn_mfma_f32_16x16x32_bf16(ah, bl, acc, 0, 0, 0);
        }
      }
      {
        float s = fmaxf(acc.x + b2v, 0.f) + fmaxf(acc.y + b2v, 0.f) +
                  fmaxf(acc.z + b2v, 0.f);
        if (q < 3) s += fmaxf(acc.w + b2v, 0.f);   // x=15 row is pad
        gapAcc += s;
      }
      const int r0 = 2 * y2 + 4;
      if (r0 <= 30) {
        int ps = s0 + 4; if (ps >= 6) ps -= 6;
        produce(r0, ps);
      }
      s0 += 2; if (s0 >= 6) s0 -= 6;
    }

    // reduce gapAcc over kc-quads (lanes m, m+16, m+32, m+48)
    gapAcc += __shfl_down(gapAcc, 32, 64);
    gapAcc += __shfl_down(gapAcc, 16, 64);
    if (lane < 16) gapv[wave * 16 + m] = gapAcc * (1.0f / 225.0f);
    __syncthreads();

    if (tid < OUTF) {
      float f = blg[tid];
#pragma unroll 8
      for (int i = 0; i < 64; ++i) f = fmaf(gapv[i], ws[WS_WLT + i * OUTF + tid], f);
      if (side == 0) {
        fstash[tid] = f;
      } else {
        float d = f - fstash[tid];
        dd = d * d;
      }
    }
    __syncthreads();           // fstash/gapv settled before next side reuses LDS
  }

  // block reduction of dd -> one atomicAdd
  dd += __shfl_down(dd, 32, 64);
  dd += __shfl_down(dd, 16, 64);
  dd += __shfl_down(dd, 8, 64);
  dd += __shfl_down(dd, 4, 64);
  dd += __shfl_down(dd, 2, 64);
  dd += __shfl_down(dd, 1, 64);
  if (lane == 0) lred[wave] = dd;
  __syncthreads();
  if (tid == 0) {
    float s = (lred[0] + lred[1]) + (lred[2] + lred[3]);
    atomicAdd(out, s * (1.0f / 131072.0f));
  }
}

extern "C" void kernel_launch(void* const* d_in, const int* in_sizes, int n_in,
                              void* d_out, int out_size, void* d_ws, size_t ws_size,
                              hipStream_t stream) {
  const float* imgG = (const float*)d_in[0];
  const float* imgS = (const float*)d_in[1];
  const float* kpG  = (const float*)d_in[2];
  const float* kpS  = (const float*)d_in[3];
  const float* w1   = (const float*)d_in[4];
  const float* b1   = (const float*)d_in[5];
  const float* w2   = (const float*)d_in[6];
  const float* b2   = (const float*)d_in[7];
  const float* wl   = (const float*)d_in[8];
  const float* bl   = (const float*)d_in[9];
  float* ws  = (float*)d_ws;
  float* out = (float*)d_out;

  hipLaunchKernelGGL(prep_kernel, dim3(32), dim3(256), 0, stream, w1, w2, wl, ws, out);
  hipLaunchKernelGGL(patch_cnn_kernel, dim3(1024), dim3(256), 0, stream,
                     imgG, imgS, kpG, kpS, b1, b2, bl, ws, out);
}